// Round 8
// baseline (225.422 us; speedup 1.0000x reference)
//
#include <hip/hip_runtime.h>

// PointMassModel: X' = [v, a - g, c*(u - a)], RK4 x 8 substeps, h = DT/8.
// Linear constant-coefficient ODE => 8 RK4 substeps collapse to one affine map
//   s8 = P^8 s0 + S Q w,  w = E u + F g   (coefficients built host-side in double).
// Pure streaming op: 172 MB real HBM per call (FETCH_SIZE halves reads on
// gfx950 -- gfx94x artifact; WRITE_SIZE exact).
//
// V9: REGISTER-DIRECT, no LDS, no barriers. Policy grid complete: all nt-read
// variants tie at ~42.5us (4.05 TB/s, 64% of copy ceiling); store policy
// indifferent; occupancy/prefetch/tile flat. Remaining structural difference
// vs the 6.5 TB/s fill kernel: the LDS round-trip + phase structure
// (HBM->VGPR->LDS->VGPR->LDS->VGPR->HBM with block barriers). Key layout
// fact: 4 envs = 36 floats = exactly 9 float4 -> a thread owning 4
// consecutive envs loads 9 contiguous aligned f32x4 (144B/lane), computes
// fully in registers (no cross-lane data needed), stores 9 f32x4. One
// uninterrupted load->compute->store stream per wave, copy-style.
// Known risk: per-instruction lane stride 144B => ~72 line-reqs/wave-instr
// (9x TA amplification); pessimistic model still gives ~57 B/cy/CU >> 10.2
// needed. L1 absorbs intra-wave line reuse; HBM traffic unchanged.
// Predict: LDS 12288->0, VGPR ~64-90, FETCH/WRITE unchanged.
//   structure was the drag -> 30-36us; TA-limited -> >50us; flat -> declare.

#define THREADS 256

typedef float f32x4 __attribute__((ext_vector_type(4)));

__device__ __forceinline__ f32x4 nt_load4(const float* p) {
    return __builtin_nontemporal_load((const f32x4*)p);
}
__device__ __forceinline__ void nt_store4(float* p, const f32x4 v) {
    __builtin_nontemporal_store(v, (f32x4*)p);
}

struct Coeffs {
    float P00, P01, P02;
    float P10, P11, P12;
    float P20, P21, P22;
    float Ku0, Ku1, Ku2;   // R[:,2] * c   (u coefficient)
    float Kg0, Kg1, Kg2;   // -R[:,1]      (g coefficient)
};

__device__ __forceinline__ void compute9(const float x[9], const float u[3],
                                         const Coeffs& cf, float r[9]) {
    #pragma unroll
    for (int k = 0; k < 3; ++k) {
        const float p = x[k];
        const float v = x[3 + k];
        const float a = x[6 + k];
        const float uu = u[k];
        const float g = (k == 2) ? -9.81f : 0.0f;
        r[k]     = cf.P00 * p + cf.P01 * v + cf.P02 * a + cf.Ku0 * uu + cf.Kg0 * g;
        r[3 + k] = cf.P10 * p + cf.P11 * v + cf.P12 * a + cf.Ku1 * uu + cf.Kg1 * g;
        r[6 + k] = cf.P20 * p + cf.P21 * v + cf.P22 * a + cf.Ku2 * uu + cf.Kg2 * g;
    }
}

__global__ __launch_bounds__(THREADS)
void pointmass_kernel(const float* __restrict__ X0,
                      const float* __restrict__ U,
                      float* __restrict__ Out,
                      int envTotal, Coeffs cf) {
    const int g4 = blockIdx.x * THREADS + threadIdx.x;   // 4-env group index
    const size_t e0 = (size_t)g4 * 4;

    if (e0 + 4 <= (size_t)envTotal) {
        const float* xp = X0 + e0 * 9;    // 36 floats, 144B-aligned
        const float* up = U  + e0 * 3;    // 12 floats, 48B-aligned
        float* op = Out + e0 * 9;

        // ---- load: 9 + 3 contiguous nt f32x4, all issued back-to-back ----
        f32x4 xv[9], uv[3];
        #pragma unroll
        for (int q = 0; q < 9; ++q) xv[q] = nt_load4(xp + 4 * q);
        #pragma unroll
        for (int q = 0; q < 3; ++q) uv[q] = nt_load4(up + 4 * q);

        // ---- unpack to scalar regs (all indices compile-time) ----
        float xs[36], us[12];
        #pragma unroll
        for (int q = 0; q < 9; ++q) {
            #pragma unroll
            for (int j = 0; j < 4; ++j) xs[4 * q + j] = xv[q][j];
        }
        #pragma unroll
        for (int q = 0; q < 3; ++q) {
            #pragma unroll
            for (int j = 0; j < 4; ++j) us[4 * q + j] = uv[q][j];
        }

        // ---- compute 4 envs entirely in registers ----
        float os[36];
        #pragma unroll
        for (int e = 0; e < 4; ++e)
            compute9(xs + 9 * e, us + 3 * e, cf, os + 9 * e);

        // ---- store: 9 contiguous nt f32x4 ----
        #pragma unroll
        for (int q = 0; q < 9; ++q) {
            f32x4 v;
            #pragma unroll
            for (int j = 0; j < 4; ++j) v[j] = os[4 * q + j];
            nt_store4(op + 4 * q, v);
        }
    } else if (e0 < (size_t)envTotal) {
        // ---- tail: scalar per-env (unused for N=2^21 but safe) ----
        for (size_t e = e0; e < (size_t)envTotal; ++e) {
            float x[9], u[3], r[9];
            #pragma unroll
            for (int q = 0; q < 9; ++q) x[q] = X0[e * 9 + q];
            #pragma unroll
            for (int k = 0; k < 3; ++k) u[k] = U[e * 3 + k];
            compute9(x, u, cf, r);
            #pragma unroll
            for (int q = 0; q < 9; ++q) Out[e * 9 + q] = r[q];
        }
    }
}

// ---------------- host-side coefficient computation ----------------
static void mat3_mul(const double A[3][3], const double B[3][3], double C[3][3]) {
    for (int i = 0; i < 3; ++i)
        for (int j = 0; j < 3; ++j) {
            double s = 0.0;
            for (int k = 0; k < 3; ++k) s += A[i][k] * B[k][j];
            C[i][j] = s;
        }
}
static void mat3_copy(const double A[3][3], double B[3][3]) {
    for (int i = 0; i < 3; ++i) for (int j = 0; j < 3; ++j) B[i][j] = A[i][j];
}

extern "C" void kernel_launch(void* const* d_in, const int* in_sizes, int n_in,
                              void* d_out, int out_size, void* d_ws, size_t ws_size,
                              hipStream_t stream) {
    const float* X0 = (const float*)d_in[0];
    const float* U  = (const float*)d_in[1];
    float* Out = (float*)d_out;
    const int envTotal = in_sizes[0] / 9;

    // --- build RK4 closed-form coefficients in double ---
    const double DT = 0.02;
    const double h = DT / 8.0;
    const double c = 0.5 / DT;                 // LMBDA / DT = 25
    double hA[3][3] = {{0, h, 0}, {0, 0, h}, {0, 0, -c * h}};

    double hA2[3][3], hA3[3][3], hA4[3][3];
    mat3_mul(hA, hA, hA2);
    mat3_mul(hA2, hA, hA3);
    mat3_mul(hA3, hA, hA4);

    double P[3][3], Q[3][3];
    for (int i = 0; i < 3; ++i)
        for (int j = 0; j < 3; ++j) {
            const double I = (i == j) ? 1.0 : 0.0;
            P[i][j] = I + hA[i][j] + hA2[i][j] / 2.0 + hA3[i][j] / 6.0 + hA4[i][j] / 24.0;
            Q[i][j] = h * (I + hA[i][j] / 2.0 + hA2[i][j] / 6.0 + hA3[i][j] / 24.0);
        }

    double P2[3][3], P4[3][3], P8[3][3];
    mat3_mul(P, P, P2);
    mat3_mul(P2, P2, P4);
    mat3_mul(P4, P4, P8);

    // S = I + P + ... + P^7 = (I+P)(I+P^2)(I+P^4)
    double IP[3][3], IP2[3][3], IP4[3][3], T[3][3], S[3][3], R[3][3];
    mat3_copy(P, IP);  mat3_copy(P2, IP2);  mat3_copy(P4, IP4);
    for (int i = 0; i < 3; ++i) { IP[i][i] += 1.0; IP2[i][i] += 1.0; IP4[i][i] += 1.0; }
    mat3_mul(IP, IP2, T);
    mat3_mul(T, IP4, S);
    mat3_mul(S, Q, R);

    Coeffs cf;
    cf.P00 = (float)P8[0][0]; cf.P01 = (float)P8[0][1]; cf.P02 = (float)P8[0][2];
    cf.P10 = (float)P8[1][0]; cf.P11 = (float)P8[1][1]; cf.P12 = (float)P8[1][2];
    cf.P20 = (float)P8[2][0]; cf.P21 = (float)P8[2][1]; cf.P22 = (float)P8[2][2];
    cf.Ku0 = (float)(R[0][2] * c); cf.Ku1 = (float)(R[1][2] * c); cf.Ku2 = (float)(R[2][2] * c);
    cf.Kg0 = (float)(-R[0][1]);    cf.Kg1 = (float)(-R[1][1]);    cf.Kg2 = (float)(-R[2][1]);

    const int groups = (envTotal + 3) / 4;
    const int blocks = (groups + THREADS - 1) / THREADS;
    pointmass_kernel<<<blocks, THREADS, 0, stream>>>(X0, U, Out, envTotal, cf);
}

// Round 9
// 149.109 us; speedup vs baseline: 1.5118x; 1.5118x over previous
//
#include <hip/hip_runtime.h>

// PointMassModel: X' = [v, a - g, c*(u - a)], RK4 x 8 substeps, h = DT/8.
// Linear constant-coefficient ODE => 8 RK4 substeps collapse to one affine map
//   s8 = P^8 s0 + S Q w,  w = E u + F g   (coefficients built host-side in double).
// Pure streaming op: 172 MB real HBM per call (FETCH halves reads on gfx950
// -- gfx94x artifact; WRITE exact).
//
// V10: wave-autonomous pipeline x nt policy (the untested combination).
// Ledger: v9 (no-LDS, 144B lane stride) -> 2.5x WRITE amplification, 113us:
// wave-contiguous access + LDS transpose is mandatory. v7 (nt/nt, phased)
// = 42.5us, which decomposes EXACTLY as serialized streams: reads 98.3MB @
// 3.2 TB/s (copy's per-direction rate) = 30.7us + writes 73.7MB @ 6.5 TB/s
// (fill rate) = 11.3us => 42.0us. Hypothesis: phase-locked block convoys
// alternate read-only / write-only DRAM epochs; copy proves concurrent R+W
// hits 6.29 TB/s summed. Fix: v3's barrier-free wave pipeline (next tile's
// nt-loads issued BEFORE current tile's nt-stores, so both streams are in
// flight continuously), CHUNK=8 for 7/8 steady-state fraction.
// Predict: FETCH/WRITE bit-identical (no amplification); kernel 31-36us if
// overlap theory right; flat ~42 -> revert v7 + declare roofline.

#define THREADS 256
#define WAVES 4            // waves per block
#define WTILE 64           // envs per wave-tile
#define CHUNK 8            // contiguous tiles per wave
#define XF4 144            // float4 per wave-tile of X / Out (64*9/4)
#define UF4 48             // float4 per wave-tile of U        (64*3/4)

typedef float f32x4 __attribute__((ext_vector_type(4)));

__device__ __forceinline__ f32x4 nt_load4(const float* p) {
    return __builtin_nontemporal_load((const f32x4*)p);
}
__device__ __forceinline__ void nt_store4(float* p, const f32x4 v) {
    __builtin_nontemporal_store(v, (f32x4*)p);
}

struct Coeffs {
    float P00, P01, P02;
    float P10, P11, P12;
    float P20, P21, P22;
    float Ku0, Ku1, Ku2;   // R[:,2] * c   (u coefficient)
    float Kg0, Kg1, Kg2;   // -R[:,1]      (g coefficient)
};

__device__ __forceinline__ void compute_env(const float* __restrict__ sx,
                                            const float* __restrict__ su,
                                            const Coeffs& cf, float r[9]) {
    #pragma unroll
    for (int k = 0; k < 3; ++k) {
        const float p = sx[k];
        const float v = sx[3 + k];
        const float a = sx[6 + k];
        const float u = su[k];
        const float g = (k == 2) ? -9.81f : 0.0f;
        r[k]     = cf.P00 * p + cf.P01 * v + cf.P02 * a + cf.Ku0 * u + cf.Kg0 * g;
        r[3 + k] = cf.P10 * p + cf.P11 * v + cf.P12 * a + cf.Ku1 * u + cf.Kg1 * g;
        r[6 + k] = cf.P20 * p + cf.P21 * v + cf.P22 * a + cf.Ku2 * u + cf.Kg2 * g;
    }
}

__global__ __launch_bounds__(THREADS)
void pointmass_kernel(const float* __restrict__ X0,
                      const float* __restrict__ U,
                      float* __restrict__ Out,
                      int envTotal, Coeffs cf) {
    // per-wave slice: 576 floats X/out + 192 floats U; double buffered.
    // 2 * 4 * 768 * 4B = 24576 B -> 6 blocks/CU ceiling (grid gives 2/CU).
    __shared__ float lds[2][WAVES][768];

    const int t = threadIdx.x;
    const int w = t >> 6;          // wave id in block
    const int l = t & 63;          // lane
    const int fullTiles = envTotal / WTILE;
    const int tileBase = (blockIdx.x * WAVES + w) * CHUNK;
    const int te = min(tileBase + CHUNK, fullTiles);

    if (tileBase < te) {
        float* const xs0 = &lds[0][w][0];
        float* const us0 = &lds[0][w][576];
        float* const xs1 = &lds[1][w][0];
        float* const us1 = &lds[1][w][576];

        // ---- prologue: stage tile tileBase into buffer 0 (wave-local) ----
        {
            const size_t xb = (size_t)tileBase * XF4;
            const size_t ub = (size_t)tileBase * UF4;
            f32x4 a0 = nt_load4((const float*)(X0) + (xb + l) * 4);
            f32x4 a1 = nt_load4((const float*)(X0) + (xb + 64 + l) * 4);
            f32x4 a2, b0;
            if (l < 16) a2 = nt_load4((const float*)(X0) + (xb + 128 + l) * 4);
            if (l < 48) b0 = nt_load4((const float*)(U) + (ub + l) * 4);
            ((f32x4*)xs0)[l]      = a0;        // compiler: counted vmcnt waits
            ((f32x4*)xs0)[64 + l] = a1;
            if (l < 16) ((f32x4*)xs0)[128 + l] = a2;
            if (l < 48) ((f32x4*)us0)[l]       = b0;
        }

        int cur = 0;
        for (int i = tileBase; i < te; ++i) {
            float* const xs  = cur ? xs1 : xs0;
            float* const us  = cur ? us1 : us0;
            float* const xsN = cur ? xs0 : xs1;
            float* const usN = cur ? us0 : us1;
            const bool haveNext = (i + 1 < te);   // wave-uniform

            // (1) issue next tile's nt-loads -> registers (in flight all iter,
            //     concurrent with this iter's stores => mixed R/W at DRAM)
            f32x4 a0, a1, a2, b0;
            if (haveNext) {
                const size_t xb = (size_t)(i + 1) * XF4;
                const size_t ub = (size_t)(i + 1) * UF4;
                a0 = nt_load4((const float*)(X0) + (xb + l) * 4);
                a1 = nt_load4((const float*)(X0) + (xb + 64 + l) * 4);
                if (l < 16) a2 = nt_load4((const float*)(X0) + (xb + 128 + l) * 4);
                if (l < 48) b0 = nt_load4((const float*)(U) + (ub + l) * 4);
            }

            // (2) compute own env; lane-private LDS slots, no sync needed
            {
                float r[9];
                compute_env(xs + l * 9, us + l * 3, cf, r);
                float* sxw = xs + l * 9;
                #pragma unroll
                for (int q = 0; q < 9; ++q) sxw[q] = r[q];
            }

            // (3) coalesced nt float4 store of tile i (lgkm wait via data dep)
            {
                const size_t ob = (size_t)i * XF4;
                nt_store4((float*)(Out) + (ob + l) * 4,      ((const f32x4*)xs)[l]);
                nt_store4((float*)(Out) + (ob + 64 + l) * 4, ((const f32x4*)xs)[64 + l]);
                if (l < 16)
                    nt_store4((float*)(Out) + (ob + 128 + l) * 4, ((const f32x4*)xs)[128 + l]);
            }

            // keep prefetch-landing below the stores: its vmcnt wait is then
            // counted (stores younger, stay in flight)
            __builtin_amdgcn_sched_barrier(0);

            // (4) land prefetch into the other buffer
            if (haveNext) {
                ((f32x4*)xsN)[l]      = a0;
                ((f32x4*)xsN)[64 + l] = a1;
                if (l < 16) ((f32x4*)xsN)[128 + l] = a2;
                if (l < 48) ((f32x4*)usN)[l]       = b0;
            }
            cur ^= 1;
        }
    }

    // ---- tail: remainder envs (none for N=2^21, but safe) ----
    const int rem0 = fullTiles * WTILE;
    if (rem0 < envTotal && blockIdx.x == gridDim.x - 1) {
        for (int e = rem0 + t; e < envTotal; e += THREADS) {
            float xr[9], ur[3], r[9];
            #pragma unroll
            for (int q = 0; q < 9; ++q) xr[q] = X0[(size_t)e * 9 + q];
            #pragma unroll
            for (int k = 0; k < 3; ++k) ur[k] = U[(size_t)e * 3 + k];
            compute_env(xr, ur, cf, r);
            #pragma unroll
            for (int q = 0; q < 9; ++q) Out[(size_t)e * 9 + q] = r[q];
        }
    }
}

// ---------------- host-side coefficient computation ----------------
static void mat3_mul(const double A[3][3], const double B[3][3], double C[3][3]) {
    for (int i = 0; i < 3; ++i)
        for (int j = 0; j < 3; ++j) {
            double s = 0.0;
            for (int k = 0; k < 3; ++k) s += A[i][k] * B[k][j];
            C[i][j] = s;
        }
}
static void mat3_copy(const double A[3][3], double B[3][3]) {
    for (int i = 0; i < 3; ++i) for (int j = 0; j < 3; ++j) B[i][j] = A[i][j];
}

extern "C" void kernel_launch(void* const* d_in, const int* in_sizes, int n_in,
                              void* d_out, int out_size, void* d_ws, size_t ws_size,
                              hipStream_t stream) {
    const float* X0 = (const float*)d_in[0];
    const float* U  = (const float*)d_in[1];
    float* Out = (float*)d_out;
    const int envTotal = in_sizes[0] / 9;

    // --- build RK4 closed-form coefficients in double ---
    const double DT = 0.02;
    const double h = DT / 8.0;
    const double c = 0.5 / DT;                 // LMBDA / DT = 25
    double hA[3][3] = {{0, h, 0}, {0, 0, h}, {0, 0, -c * h}};

    double hA2[3][3], hA3[3][3], hA4[3][3];
    mat3_mul(hA, hA, hA2);
    mat3_mul(hA2, hA, hA3);
    mat3_mul(hA3, hA, hA4);

    double P[3][3], Q[3][3];
    for (int i = 0; i < 3; ++i)
        for (int j = 0; j < 3; ++j) {
            const double I = (i == j) ? 1.0 : 0.0;
            P[i][j] = I + hA[i][j] + hA2[i][j] / 2.0 + hA3[i][j] / 6.0 + hA4[i][j] / 24.0;
            Q[i][j] = h * (I + hA[i][j] / 2.0 + hA2[i][j] / 6.0 + hA3[i][j] / 24.0);
        }

    double P2[3][3], P4[3][3], P8[3][3];
    mat3_mul(P, P, P2);
    mat3_mul(P2, P2, P4);
    mat3_mul(P4, P4, P8);

    // S = I + P + ... + P^7 = (I+P)(I+P^2)(I+P^4)
    double IP[3][3], IP2[3][3], IP4[3][3], T[3][3], S[3][3], R[3][3];
    mat3_copy(P, IP);  mat3_copy(P2, IP2);  mat3_copy(P4, IP4);
    for (int i = 0; i < 3; ++i) { IP[i][i] += 1.0; IP2[i][i] += 1.0; IP4[i][i] += 1.0; }
    mat3_mul(IP, IP2, T);
    mat3_mul(T, IP4, S);
    mat3_mul(S, Q, R);

    Coeffs cf;
    cf.P00 = (float)P8[0][0]; cf.P01 = (float)P8[0][1]; cf.P02 = (float)P8[0][2];
    cf.P10 = (float)P8[1][0]; cf.P11 = (float)P8[1][1]; cf.P12 = (float)P8[1][2];
    cf.P20 = (float)P8[2][0]; cf.P21 = (float)P8[2][1]; cf.P22 = (float)P8[2][2];
    cf.Ku0 = (float)(R[0][2] * c); cf.Ku1 = (float)(R[1][2] * c); cf.Ku2 = (float)(R[2][2] * c);
    cf.Kg0 = (float)(-R[0][1]);    cf.Kg1 = (float)(-R[1][1]);    cf.Kg2 = (float)(-R[2][1]);

    const int fullTiles = envTotal / WTILE;
    const int wavesNeeded = (fullTiles + CHUNK - 1) / CHUNK;
    int blocks = (wavesNeeded + WAVES - 1) / WAVES;
    if (blocks < 1) blocks = 1;
    pointmass_kernel<<<blocks, THREADS, 0, stream>>>(X0, U, Out, envTotal, cf);
}

// Round 10
// 144.981 us; speedup vs baseline: 1.5548x; 1.0285x over previous
//
#include <hip/hip_runtime.h>

// PointMassModel: X' = [v, a - g, c*(u - a)], RK4 x 8 substeps, h = DT/8.
// Linear constant-coefficient ODE => 8 RK4 substeps collapse to one affine map
//   s8 = P^8 s0 + S Q w,  w = E u + F g   (coefficients built host-side in double).
// Pure streaming op: 176 MB real HBM per call (FETCH halves reads on gfx950
// -- gfx94x artifact; WRITE exact).
//
// V11: global_load_lds staging (LDS-DMA), the one untested mechanism.
// Ledger: policy grid complete (nt-read +7us is the only real lever; store
// policy indifferent); structure grid complete (phased/dbuf/wave-pipeline/
// no-LDS all <= v7=42.5us or worse; v10 overlap probe regressed to 47us);
// occupancy 8-68% flat. All variants share one path: HBM->VGPR->ds_write
// staging. global_load_lds replaces it with fire-and-forget wave DMA
// (no VGPR writeback, no ds_write, different read-request profile at TCC/EA)
// -- the documented 1.69x GEMM-staging lever (m97), never auto-emitted.
// Our LDS layout is exactly the DMA shape: linear, wave-uniform base + l*16.
// Single change vs v7; compute + nt-store epilogue identical.
// Predict: FETCH/WRITE bit-identical; VGPR ~16-24; dur 34-39us if the
// read path was the drag; flat +-2% -> revert v7, declare ~4.15 TB/s roofline.

#define ENVS_PER_BLOCK 256
#define THREADS 256

typedef float f32x4 __attribute__((ext_vector_type(4)));
typedef __attribute__((address_space(1))) const void glb_v;
typedef __attribute__((address_space(3))) void lds_v;

__device__ __forceinline__ void dma16(const float* g, float* l) {
    // wave-collective: deposits 64 lanes x 16B at ldsbase + lane*16,
    // from per-lane global address g. aux=2 (SLC/nt hint; policy-safe).
    __builtin_amdgcn_global_load_lds((glb_v*)g, (lds_v*)l, 16, 0, 2);
}
__device__ __forceinline__ void nt_store4(float* p, const f32x4 v) {
    __builtin_nontemporal_store(v, (f32x4*)p);
}

struct Coeffs {
    float P00, P01, P02;
    float P10, P11, P12;
    float P20, P21, P22;
    float Ku0, Ku1, Ku2;   // R[:,2] * c   (u coefficient)
    float Kg0, Kg1, Kg2;   // -R[:,1]      (g coefficient)
};

__device__ __forceinline__ void compute_env(const float* __restrict__ sx,
                                            const float* __restrict__ su,
                                            const Coeffs& cf, float r[9]) {
    #pragma unroll
    for (int k = 0; k < 3; ++k) {
        const float p = sx[k];
        const float v = sx[3 + k];
        const float a = sx[6 + k];
        const float u = su[k];
        const float g = (k == 2) ? -9.81f : 0.0f;
        r[k]     = cf.P00 * p + cf.P01 * v + cf.P02 * a + cf.Ku0 * u + cf.Kg0 * g;
        r[3 + k] = cf.P10 * p + cf.P11 * v + cf.P12 * a + cf.Ku1 * u + cf.Kg1 * g;
        r[6 + k] = cf.P20 * p + cf.P21 * v + cf.P22 * a + cf.Ku2 * u + cf.Kg2 * g;
    }
}

__global__ __launch_bounds__(THREADS)
void pointmass_kernel(const float* __restrict__ X0,
                      const float* __restrict__ U,
                      float* __restrict__ Out,
                      int envTotal, Coeffs cf) {
    __shared__ float s_x[ENVS_PER_BLOCK * 9];   // 9216 B = 9 DMA chunks of 1024B
    __shared__ float s_u[ENVS_PER_BLOCK * 3];   // 3072 B = 3 DMA chunks

    const int t = threadIdx.x;
    const int w = t >> 6;          // wave id (0..3), wave-uniform
    const int l = t & 63;          // lane
    const int blockBase = blockIdx.x * ENVS_PER_BLOCK;
    const int envsHere = min(ENVS_PER_BLOCK, envTotal - blockBase);

    if (envsHere == ENVS_PER_BLOCK) {
        const float* xg = X0 + (size_t)blockBase * 9;   // 9216B-aligned
        const float* ug = U  + (size_t)blockBase * 3;   // 3072B-aligned
        float* og = Out + (size_t)blockBase * 9;

        // ---- stage via LDS-DMA: 3 wave-collective calls per wave ----
        // X chunks 2w, 2w+1 by wave w; chunk 8 by wave 0; U chunk w-1 by waves 1-3.
        dma16(xg + 512 * w + 4 * l,       s_x + 512 * w);
        dma16(xg + 512 * w + 256 + 4 * l, s_x + 512 * w + 256);
        if (w == 0) dma16(xg + 2048 + 4 * l,            s_x + 2048);
        else        dma16(ug + (w - 1) * 256 + 4 * l,   s_u + (w - 1) * 256);
        __syncthreads();    // drains vmcnt (DMA completion) + barrier

        // ---- compute: 1 env/thread; stride-9-word LDS = 2-way alias (free) --
        float r[9];
        compute_env(s_x + t * 9, s_u + t * 3, cf, r);
        #pragma unroll
        for (int i = 0; i < 9; ++i) s_x[t * 9 + i] = r[i];
        __syncthreads();

        // ---- store: cooperative coalesced nt float4 ----
        {
            const f32x4 v0 = ((const f32x4*)s_x)[t];
            const f32x4 v1 = ((const f32x4*)s_x)[t + 256];
            nt_store4(og + t * 4, v0);
            nt_store4(og + (t + 256) * 4, v1);
            if (t < 64) {
                const f32x4 v2 = ((const f32x4*)s_x)[t + 512];
                nt_store4(og + (t + 512) * 4, v2);
            }
        }
    } else {
        // ---- tail path (unused for N=2^21 but safe) ----
        for (int j = t; j < envsHere * 9; j += THREADS)
            s_x[j] = X0[(size_t)blockBase * 9 + j];
        for (int j = t; j < envsHere * 3; j += THREADS)
            s_u[j] = U[(size_t)blockBase * 3 + j];
        __syncthreads();
        if (t < envsHere) {
            float r[9];
            compute_env(s_x + t * 9, s_u + t * 3, cf, r);
            #pragma unroll
            for (int i = 0; i < 9; ++i)
                Out[((size_t)blockBase + t) * 9 + i] = r[i];
        }
    }
}

// ---------------- host-side coefficient computation ----------------
static void mat3_mul(const double A[3][3], const double B[3][3], double C[3][3]) {
    for (int i = 0; i < 3; ++i)
        for (int j = 0; j < 3; ++j) {
            double s = 0.0;
            for (int k = 0; k < 3; ++k) s += A[i][k] * B[k][j];
            C[i][j] = s;
        }
}
static void mat3_copy(const double A[3][3], double B[3][3]) {
    for (int i = 0; i < 3; ++i) for (int j = 0; j < 3; ++j) B[i][j] = A[i][j];
}

extern "C" void kernel_launch(void* const* d_in, const int* in_sizes, int n_in,
                              void* d_out, int out_size, void* d_ws, size_t ws_size,
                              hipStream_t stream) {
    const float* X0 = (const float*)d_in[0];
    const float* U  = (const float*)d_in[1];
    float* Out = (float*)d_out;
    const int envTotal = in_sizes[0] / 9;

    // --- build RK4 closed-form coefficients in double ---
    const double DT = 0.02;
    const double h = DT / 8.0;
    const double c = 0.5 / DT;                 // LMBDA / DT = 25
    double hA[3][3] = {{0, h, 0}, {0, 0, h}, {0, 0, -c * h}};

    double hA2[3][3], hA3[3][3], hA4[3][3];
    mat3_mul(hA, hA, hA2);
    mat3_mul(hA2, hA, hA3);
    mat3_mul(hA3, hA, hA4);

    double P[3][3], Q[3][3];
    for (int i = 0; i < 3; ++i)
        for (int j = 0; j < 3; ++j) {
            const double I = (i == j) ? 1.0 : 0.0;
            P[i][j] = I + hA[i][j] + hA2[i][j] / 2.0 + hA3[i][j] / 6.0 + hA4[i][j] / 24.0;
            Q[i][j] = h * (I + hA[i][j] / 2.0 + hA2[i][j] / 6.0 + hA3[i][j] / 24.0);
        }

    double P2[3][3], P4[3][3], P8[3][3];
    mat3_mul(P, P, P2);
    mat3_mul(P2, P2, P4);
    mat3_mul(P4, P4, P8);

    // S = I + P + ... + P^7 = (I+P)(I+P^2)(I+P^4)
    double IP[3][3], IP2[3][3], IP4[3][3], T[3][3], S[3][3], R[3][3];
    mat3_copy(P, IP);  mat3_copy(P2, IP2);  mat3_copy(P4, IP4);
    for (int i = 0; i < 3; ++i) { IP[i][i] += 1.0; IP2[i][i] += 1.0; IP4[i][i] += 1.0; }
    mat3_mul(IP, IP2, T);
    mat3_mul(T, IP4, S);
    mat3_mul(S, Q, R);

    Coeffs cf;
    cf.P00 = (float)P8[0][0]; cf.P01 = (float)P8[0][1]; cf.P02 = (float)P8[0][2];
    cf.P10 = (float)P8[1][0]; cf.P11 = (float)P8[1][1]; cf.P12 = (float)P8[1][2];
    cf.P20 = (float)P8[2][0]; cf.P21 = (float)P8[2][1]; cf.P22 = (float)P8[2][2];
    cf.Ku0 = (float)(R[0][2] * c); cf.Ku1 = (float)(R[1][2] * c); cf.Ku2 = (float)(R[2][2] * c);
    cf.Kg0 = (float)(-R[0][1]);    cf.Kg1 = (float)(-R[1][1]);    cf.Kg2 = (float)(-R[2][1]);

    const int blocks = (envTotal + ENVS_PER_BLOCK - 1) / ENVS_PER_BLOCK;
    pointmass_kernel<<<blocks, THREADS, 0, stream>>>(X0, U, Out, envTotal, cf);
}